// Round 4
// baseline (362.621 us; speedup 1.0000x reference)
//
#include <hip/hip_runtime.h>
#include <stdint.h>

typedef unsigned short u16;
typedef unsigned int   u32;
typedef unsigned long long u64;

using bf16x8 = __attribute__((ext_vector_type(8))) __bf16;
using f32x4  = __attribute__((ext_vector_type(4))) float;

#define NROWS 32768   // B*H*W*D / 256 rows after reshape(-1,256)
#define NDIM  256
#define KCODES 8192
#define ND_TOT 8388608
#define NT 32         // n-tiles (of 128 codes) per block (half the codebook)

__device__ __forceinline__ u32 f2bf(float f) {
    u32 u = __float_as_uint(f);
    return (u + 0x7FFFu + ((u >> 16) & 1u)) >> 16;   // RNE bf16
}

// ---------------- prep: codebook -> bf16 ----------------
__global__ __launch_bounds__(64) void prep_cb_kernel(const float* __restrict__ cb,
                                                     u16* __restrict__ cbb) {
    int k = blockIdx.x;          // one wave per code row
    int lane = threadIdx.x;
    int base = k * NDIM + lane * 4;
    float4 a = *(const float4*)(cb + base);
    uint2 o;
    o.x = f2bf(a.x) | (f2bf(a.y) << 16);
    o.y = f2bf(a.z) | (f2bf(a.w) << 16);
    *(uint2*)(cbb + base) = o;
}

// ---------------- fused GEMM + argmax, barrier-free ----------------
// Block = 128 m-rows x half codebook. A (64 rows x 256 K bf16/wave) in regs.
// B loaded DIRECTLY global->VGPR in MFMA B-operand layout (no LDS, no
// __syncthreads): 256 steps of [4x global_load_dwordx4 prefetch next step |
// 16 MFMAs on current step], one-step software pipeline -> compiler emits
// fine-grained s_waitcnt vmcnt(4) (AITER pattern), no barrier drains.
// wm-wave-pair reads identical B addresses -> L1 dedup. Packed-key argmax
// (score|col in mantissa low13) stays in regs; one reduction/store per row.
__global__ __launch_bounds__(256, 2) void vq_scores_kernel(const float* __restrict__ z,
                                                           const u16* __restrict__ cbb,
                                                           u32* __restrict__ slots) {
    int bid  = blockIdx.x;
    int half = bid & 1;
    int m0   = (bid >> 1) * 128;
    int nbase = half * (KCODES / 2);
    int tid  = threadIdx.x;
    int lane = tid & 63;
    int w    = tid >> 6;         // 2x2 wave grid
    int wm = w >> 1, wn = w & 1;
    int l15 = lane & 15, quad = lane >> 4;

    // ---- one-time A prologue: wave's 64 rows x 256 K -> bf16 registers ----
    bf16x8 A[8][4];              // [kstep(32-wide)][mfrag(16 rows)] = 128 VGPRs
    {
        const float* zb = z + (size_t)(m0 + wm * 64) * NDIM;
        #pragma unroll
        for (int ks = 0; ks < 8; ks++)
            #pragma unroll
            for (int i = 0; i < 4; i++) {
                const float* p = zb + (size_t)(i * 16 + l15) * NDIM + ks * 32 + quad * 8;
                float4 x = *(const float4*)p;
                float4 y = *(const float4*)(p + 4);
                union { u32 u[4]; bf16x8 v; } c;
                c.u[0] = f2bf(x.x) | (f2bf(x.y) << 16);
                c.u[1] = f2bf(x.z) | (f2bf(x.w) << 16);
                c.u[2] = f2bf(y.x) | (f2bf(y.y) << 16);
                c.u[3] = f2bf(y.z) | (f2bf(y.w) << 16);
                A[ks][i] = c.v;
            }
    }

    const char* cbase = (const char*)cbb;
    // byte offsets for j=0..3 B-frag loads (SGPR base + 32b voffset form;
    // cbb is 4MB so offsets fit u32). Lane's element: row nbase+wn*64+j*16+l15,
    // k-chunk quad*8.
    u32 off[4];
    #pragma unroll
    for (int j = 0; j < 4; j++)
        off[j] = (u32)(((nbase + wn * 64 + j * 16 + l15) * NDIM + quad * 8) * 2);

    bf16x8 bc[4], bn[4];
    #pragma unroll
    for (int j = 0; j < 4; j++) bc[j] = *(const bf16x8*)(cbase + off[j]);
    #pragma unroll
    for (int j = 0; j < 4; j++) off[j] += 64;   // -> addr of step 1

    f32x4 acc[4][4];
    float mkey[16];
    #pragma unroll
    for (int s = 0; s < 16; s++) mkey[s] = 0.f;

    #pragma unroll 1
    for (int t = 0; t < NT; t++) {
        // acc init = +0.25 bias => scores positive => float order == int order
        #pragma unroll
        for (int i = 0; i < 4; i++)
            #pragma unroll
            for (int j = 0; j < 4; j++)
                acc[i][j] = (f32x4){0.25f, 0.25f, 0.25f, 0.25f};

        #pragma unroll
        for (int kk = 0; kk < 8; kk++) {
            // prefetch next step's 4 B-frags (skip only at the very last step)
            if (kk < 7 || t < NT - 1) {
                #pragma unroll
                for (int j = 0; j < 4; j++)
                    bn[j] = *(const bf16x8*)(cbase + off[j]);
            }
            // advance offsets: addr(s+1)->addr(s+2); tile cross when (s+1).kk==7
            u32 inc = (kk == 6) ? (u32)(128 * NDIM * 2 - 7 * 64) : 64u;
            #pragma unroll
            for (int j = 0; j < 4; j++) off[j] += inc;

            #pragma unroll
            for (int i = 0; i < 4; i++)
                #pragma unroll
                for (int j = 0; j < 4; j++)
                    acc[i][j] = __builtin_amdgcn_mfma_f32_16x16x32_bf16(
                                    A[kk][i], bc[j], acc[i][j], 0, 0, 0);
            #pragma unroll
            for (int j = 0; j < 4; j++) bc[j] = bn[j];
        }

        // packed-key argmax update: 2 VALU per element (v_and_or_b32 + v_max_f32)
        int cb0 = nbase + t * 128 + wn * 64 + l15;
        #pragma unroll
        for (int i = 0; i < 4; i++)
            #pragma unroll
            for (int r = 0; r < 4; r++) {
                int s = i * 4 + r;
                #pragma unroll
                for (int j = 0; j < 4; j++) {
                    u32 p = (__float_as_uint(acc[i][j][r]) & 0xFFFFE000u) | (u32)(cb0 + j * 16);
                    mkey[s] = fmaxf(mkey[s], __uint_as_float(p));
                }
            }
    }

    // one-time reduction across the 16 col-lanes; plain u32 store per row
    #pragma unroll
    for (int s = 0; s < 16; s++) {
        float v = mkey[s];
        #pragma unroll
        for (int sh = 1; sh < 16; sh <<= 1)
            v = fmaxf(v, __shfl_xor(v, sh, 64));
        if (l15 == s) {   // one writer per 16-lane group (4 quads -> 4 rows)
            int i = s >> 2, r = s & 3;
            int row = m0 + wm * 64 + i * 16 + quad * 4 + r;
            slots[(size_t)(half * 2 + wn) * NROWS + row] = __float_as_uint(v);
        }
    }
}

// ---------------- gather + straight-through + loss partials ----------------
__global__ __launch_bounds__(256) void gather_loss_kernel(const float* __restrict__ z,
                                                          const float* __restrict__ cb,
                                                          const u32* __restrict__ slots,
                                                          float* __restrict__ out,
                                                          float* __restrict__ part) {
    __shared__ u32 lidx[16];
    __shared__ float partial[4];
    int tid = threadIdx.x;
    int n0 = blockIdx.x * 16;                 // 16 rows per block
    if (tid < 16) {
        int row = n0 + tid;
        u32 k0 = slots[row];
        u32 k1 = slots[(size_t)NROWS + row];
        u32 k2 = slots[(size_t)2 * NROWS + row];
        u32 k3 = slots[(size_t)3 * NROWS + row];
        u32 a = k0 > k1 ? k0 : k1;
        u32 b = k2 > k3 ? k2 : k3;
        lidx[tid] = (a > b ? a : b) & 0x1FFFu;   // low 13 bits = argmax col
    }
    __syncthreads();
    int lane = tid & 63;
    int w = tid >> 6;
    int d = lane * 4;
    float s = 0.f;
    #pragma unroll
    for (int g = 0; g < 4; g++) {
        int rl = g * 4 + w;
        size_t zoff = (size_t)(n0 + rl) * NDIM + d;
        u32 idx = lidx[rl];
        float4 zv = *(const float4*)(z + zoff);
        float4 qv = *(const float4*)(cb + (size_t)idx * NDIM + d);
        float4 o;
        o.x = zv.x + (qv.x - zv.x);           // straight-through, matches ref fp ops
        o.y = zv.y + (qv.y - zv.y);
        o.z = zv.z + (qv.z - zv.z);
        o.w = zv.w + (qv.w - zv.w);
        *(float4*)(out + zoff) = o;
        float dx = zv.x - qv.x, dy = zv.y - qv.y, dz = zv.z - qv.z, dw = zv.w - qv.w;
        s += dx*dx + dy*dy + dz*dz + dw*dw;
    }
    #pragma unroll
    for (int off = 32; off > 0; off >>= 1) s += __shfl_down(s, off, 64);
    if (lane == 0) partial[w] = s;
    __syncthreads();
    if (tid == 0)
        part[blockIdx.x] = (partial[0] + partial[1]) + (partial[2] + partial[3]);
}

// ---------------- final loss reduction (2048 partials) ----------------
__global__ __launch_bounds__(256) void loss_reduce_kernel(const float* __restrict__ part,
                                                          float* __restrict__ loss) {
    __shared__ float ps[4];
    int tid = threadIdx.x;
    float s = 0.f;
    #pragma unroll
    for (int k = 0; k < 8; k++) s += part[tid + k * 256];
    #pragma unroll
    for (int off = 32; off > 0; off >>= 1) s += __shfl_down(s, off, 64);
    int lane = tid & 63, w = tid >> 6;
    if (lane == 0) ps[w] = s;
    __syncthreads();
    if (tid == 0)
        loss[0] = ((ps[0] + ps[1]) + (ps[2] + ps[3])) * (1.25f / 8388608.f);
}

extern "C" void kernel_launch(void* const* d_in, const int* in_sizes, int n_in,
                              void* d_out, int out_size, void* d_ws, size_t ws_size,
                              hipStream_t stream) {
    const float* z  = (const float*)d_in[0];   // 8*256*64*64 fp32
    const float* cb = (const float*)d_in[1];   // 8192*256 fp32
    float* out = (float*)d_out;                // 8388608 quantized_st + 1 loss

    char* ws = (char*)d_ws;
    u16* cbb    = (u16*)ws;                                 // 4 MB
    u32* slots  = (u32*)(ws + 4194304);                     // 512 KB (4 slots/row)
    float* part = (float*)(ws + 4194304 + 524288);          // 8 KB
    float* loss = out + ND_TOT;

    prep_cb_kernel<<<KCODES, 64, 0, stream>>>(cb, cbb);
    vq_scores_kernel<<<(NROWS / 128) * 2, 256, 0, stream>>>(z, cbb, slots);
    gather_loss_kernel<<<NROWS / 16, 256, 0, stream>>>(z, cb, slots, out, part);
    loss_reduce_kernel<<<1, 256, 0, stream>>>(part, loss);
}

// Round 5
// 220.487 us; speedup vs baseline: 1.6446x; 1.6446x over previous
//
#include <hip/hip_runtime.h>
#include <stdint.h>

typedef unsigned short u16;
typedef unsigned int   u32;
typedef unsigned long long u64;

using bf16x8 = __attribute__((ext_vector_type(8))) __bf16;
using f32x4  = __attribute__((ext_vector_type(4))) float;

typedef __attribute__((address_space(1))) const void as1_void;
typedef __attribute__((address_space(3))) void       as3_void;

#define NROWS 32768   // B*H*W*D / 256 rows after reshape(-1,256)
#define NDIM  256
#define KCODES 8192
#define ND_TOT 8388608
#define NT 32         // n-tiles (of 128 codes) per block (half the codebook)

__device__ __forceinline__ u32 f2bf(float f) {
    u32 u = __float_as_uint(f);
    return (u + 0x7FFFu + ((u >> 16) & 1u)) >> 16;   // RNE bf16
}

// ---------------- prep: codebook -> bf16 ----------------
__global__ __launch_bounds__(64) void prep_cb_kernel(const float* __restrict__ cb,
                                                     u16* __restrict__ cbb) {
    int k = blockIdx.x;          // one wave per code row
    int lane = threadIdx.x;
    int base = k * NDIM + lane * 4;
    float4 a = *(const float4*)(cb + base);
    uint2 o;
    o.x = f2bf(a.x) | (f2bf(a.y) << 16);
    o.y = f2bf(a.z) | (f2bf(a.w) << 16);
    *(uint2*)(cbb + base) = o;
}

// ---------------- fused GEMM + argmax, drain-free pipeline ----------------
// Block = 128 m-rows x half codebook. A (64 rows x 256 K bf16/wave) in regs.
// B streams through a 4-buffer ring of 16KB chunks (128 codes x 64 K), staged
// TWO intervals ahead via global_load_lds. Sync = raw s_barrier preceded by
// manual s_waitcnt vmcnt(4): retires all but the newest 4 DMA loads => chunk
// c+1 is guaranteed LDS-resident while chunk c+2's DMA stays in flight across
// the barrier (AITER pattern; m139 precedent). No vmcnt(0) drain anywhere.
// Verified-unchanged: A prologue, XOR swizzle (0 conflicts), frag layouts,
// packed-key argmax (score|col in low 13 mantissa bits).
__global__ __launch_bounds__(256, 2) void vq_scores_kernel(const float* __restrict__ z,
                                                           const u16* __restrict__ cbb,
                                                           u32* __restrict__ slots) {
    __shared__ __align__(16) u16 Bs[4][128 * 64];    // 4 x 16 KB ring

    int bid  = blockIdx.x;
    int half = bid & 1;
    int m0   = (bid >> 1) * 128;
    int nbase = half * (KCODES / 2);
    int tid  = threadIdx.x;
    int lane = tid & 63;
    int w    = tid >> 6;         // 2x2 wave grid
    int wm = w >> 1, wn = w & 1;
    int l15 = lane & 15, quad = lane >> 4;

    // ---- one-time A prologue: wave's 64 rows x 256 K -> bf16 registers ----
    bf16x8 A[8][4];              // [kstep(32-wide)][mfrag(16 rows)] = 128 VGPRs
    {
        const float* zb = z + (size_t)(m0 + wm * 64) * NDIM;
        #pragma unroll
        for (int ks = 0; ks < 8; ks++)
            #pragma unroll
            for (int i = 0; i < 4; i++) {
                const float* p = zb + (size_t)(i * 16 + l15) * NDIM + ks * 32 + quad * 8;
                float4 x = *(const float4*)p;
                float4 y = *(const float4*)(p + 4);
                union { u32 u[4]; bf16x8 v; } c;
                c.u[0] = f2bf(x.x) | (f2bf(x.y) << 16);
                c.u[1] = f2bf(x.z) | (f2bf(x.w) << 16);
                c.u[2] = f2bf(y.x) | (f2bf(y.y) << 16);
                c.u[3] = f2bf(y.z) | (f2bf(y.w) << 16);
                A[ks][i] = c.v;
            }
    }

    // stage chunk cw (tile cw>>2, K-window (cw&3)*64): 4 global_load_lds/wave,
    // verified XOR swizzle, dest = wave-uniform base + lane*16
    auto stage = [&](int cw) {
        int tile = cw >> 2, k64 = cw & 3;
        const u16* src = cbb + (size_t)(nbase + tile * 128) * NDIM + k64 * 64;
        #pragma unroll
        for (int s2 = 0; s2 < 2; s2++)       // 32-K sub-windows
            #pragma unroll
            for (int t2 = 0; t2 < 2; t2++) {
                int e = t2 * 256 + w * 64 + lane;     // 16B chunk id in sub-window
                int r = e >> 2;                       // B row (code)
                int cg = (e & 3) ^ ((r >> 1) & 3);    // swizzled k-chunk
                const u16* g = src + (size_t)r * NDIM + s2 * 32 + cg * 8;
                int ldsoff = (cw & 3) * 16384 + s2 * 8192 + (t2 * 256 + w * 64) * 16;
                __builtin_amdgcn_global_load_lds((as1_void*)g,
                    (as3_void*)((char*)&Bs[0][0] + ldsoff), 16, 0, 0);
            }
    };

    f32x4 acc[4][4];
    float mkey[16];
    #pragma unroll
    for (int s = 0; s < 16; s++) mkey[s] = 0.f;

    stage(0);
    stage(1);

    #pragma unroll 1
    for (int t = 0; t < NT; t++) {
        // acc init = +0.25 bias => scores positive => float order == int order
        #pragma unroll
        for (int i = 0; i < 4; i++)
            #pragma unroll
            for (int j = 0; j < 4; j++)
                acc[i][j] = (f32x4){0.25f, 0.25f, 0.25f, 0.25f};

        #pragma unroll
        for (int q = 0; q < 4; q++) {        // 64-K chunks of this tile
            int ci = t * 4 + q;
            stage((ci + 2) & 127);           // wrap keeps waits uniform; dummy
                                             // restage lands in a long-dead buf
            // retire all but newest 4 DMAs (chunk ci+1 resident), raw barrier:
            // chunk ci+2 stays in flight across it. No drain.
            __asm__ volatile("s_waitcnt vmcnt(4)\n\ts_barrier" ::: "memory");

            #pragma unroll
            for (int kk = 0; kk < 2; kk++) {
                bf16x8 bg[4];
                #pragma unroll
                for (int j = 0; j < 4; j++) {
                    int rb = wn * 64 + j * 16 + l15;
                    bg[j] = *(const bf16x8*)((const char*)&Bs[0][0]
                            + (ci & 3) * 16384 + kk * 8192 + rb * 64
                            + ((quad ^ ((rb >> 1) & 3)) << 4));
                }
                #pragma unroll
                for (int i = 0; i < 4; i++)
                    #pragma unroll
                    for (int j = 0; j < 4; j++)
                        acc[i][j] = __builtin_amdgcn_mfma_f32_16x16x32_bf16(
                                        A[(ci & 3) * 2 + kk][i], bg[j], acc[i][j], 0, 0, 0);
            }
        }

        // packed-key argmax update: 2 VALU per element (v_and_or_b32 + v_max_f32)
        int cb0 = nbase + t * 128 + wn * 64 + l15;
        #pragma unroll
        for (int i = 0; i < 4; i++)
            #pragma unroll
            for (int r = 0; r < 4; r++) {
                int s = i * 4 + r;
                #pragma unroll
                for (int j = 0; j < 4; j++) {
                    u32 p = (__float_as_uint(acc[i][j][r]) & 0xFFFFE000u) | (u32)(cb0 + j * 16);
                    mkey[s] = fmaxf(mkey[s], __uint_as_float(p));
                }
            }
    }

    // one-time reduction across the 16 col-lanes; plain u32 store per row
    #pragma unroll
    for (int s = 0; s < 16; s++) {
        float v = mkey[s];
        #pragma unroll
        for (int sh = 1; sh < 16; sh <<= 1)
            v = fmaxf(v, __shfl_xor(v, sh, 64));
        if (l15 == s) {   // one writer per 16-lane group (4 quads -> 4 rows)
            int i = s >> 2, r = s & 3;
            int row = m0 + wm * 64 + i * 16 + quad * 4 + r;
            slots[(size_t)(half * 2 + wn) * NROWS + row] = __float_as_uint(v);
        }
    }
}

// ---------------- gather + straight-through + loss partials ----------------
__global__ __launch_bounds__(256) void gather_loss_kernel(const float* __restrict__ z,
                                                          const float* __restrict__ cb,
                                                          const u32* __restrict__ slots,
                                                          float* __restrict__ out,
                                                          float* __restrict__ part) {
    __shared__ u32 lidx[16];
    __shared__ float partial[4];
    int tid = threadIdx.x;
    int n0 = blockIdx.x * 16;                 // 16 rows per block
    if (tid < 16) {
        int row = n0 + tid;
        u32 k0 = slots[row];
        u32 k1 = slots[(size_t)NROWS + row];
        u32 k2 = slots[(size_t)2 * NROWS + row];
        u32 k3 = slots[(size_t)3 * NROWS + row];
        u32 a = k0 > k1 ? k0 : k1;
        u32 b = k2 > k3 ? k2 : k3;
        lidx[tid] = (a > b ? a : b) & 0x1FFFu;   // low 13 bits = argmax col
    }
    __syncthreads();
    int lane = tid & 63;
    int w = tid >> 6;
    int d = lane * 4;
    float s = 0.f;
    #pragma unroll
    for (int g = 0; g < 4; g++) {
        int rl = g * 4 + w;
        size_t zoff = (size_t)(n0 + rl) * NDIM + d;
        u32 idx = lidx[rl];
        float4 zv = *(const float4*)(z + zoff);
        float4 qv = *(const float4*)(cb + (size_t)idx * NDIM + d);
        float4 o;
        o.x = zv.x + (qv.x - zv.x);           // straight-through, matches ref fp ops
        o.y = zv.y + (qv.y - zv.y);
        o.z = zv.z + (qv.z - zv.z);
        o.w = zv.w + (qv.w - zv.w);
        *(float4*)(out + zoff) = o;
        float dx = zv.x - qv.x, dy = zv.y - qv.y, dz = zv.z - qv.z, dw = zv.w - qv.w;
        s += dx*dx + dy*dy + dz*dz + dw*dw;
    }
    #pragma unroll
    for (int off = 32; off > 0; off >>= 1) s += __shfl_down(s, off, 64);
    if (lane == 0) partial[w] = s;
    __syncthreads();
    if (tid == 0)
        part[blockIdx.x] = (partial[0] + partial[1]) + (partial[2] + partial[3]);
}

// ---------------- final loss reduction (2048 partials) ----------------
__global__ __launch_bounds__(256) void loss_reduce_kernel(const float* __restrict__ part,
                                                          float* __restrict__ loss) {
    __shared__ float ps[4];
    int tid = threadIdx.x;
    float s = 0.f;
    #pragma unroll
    for (int k = 0; k < 8; k++) s += part[tid + k * 256];
    #pragma unroll
    for (int off = 32; off > 0; off >>= 1) s += __shfl_down(s, off, 64);
    int lane = tid & 63, w = tid >> 6;
    if (lane == 0) ps[w] = s;
    __syncthreads();
    if (tid == 0)
        loss[0] = ((ps[0] + ps[1]) + (ps[2] + ps[3])) * (1.25f / 8388608.f);
}

extern "C" void kernel_launch(void* const* d_in, const int* in_sizes, int n_in,
                              void* d_out, int out_size, void* d_ws, size_t ws_size,
                              hipStream_t stream) {
    const float* z  = (const float*)d_in[0];   // 8*256*64*64 fp32
    const float* cb = (const float*)d_in[1];   // 8192*256 fp32
    float* out = (float*)d_out;                // 8388608 quantized_st + 1 loss

    char* ws = (char*)d_ws;
    u16* cbb    = (u16*)ws;                                 // 4 MB
    u32* slots  = (u32*)(ws + 4194304);                     // 512 KB (4 slots/row)
    float* part = (float*)(ws + 4194304 + 524288);          // 8 KB
    float* loss = out + ND_TOT;

    prep_cb_kernel<<<KCODES, 64, 0, stream>>>(cb, cbb);
    vq_scores_kernel<<<(NROWS / 128) * 2, 256, 0, stream>>>(z, cbb, slots);
    gather_loss_kernel<<<NROWS / 16, 256, 0, stream>>>(z, cb, slots, out, part);
    loss_reduce_kernel<<<1, 256, 0, stream>>>(part, loss);
}

// Round 6
// 171.879 us; speedup vs baseline: 2.1098x; 1.2828x over previous
//
#include <hip/hip_runtime.h>
#include <stdint.h>

typedef unsigned short u16;
typedef unsigned int   u32;
typedef unsigned long long u64;

using i32x8 = __attribute__((ext_vector_type(8))) int;
using f32x4 = __attribute__((ext_vector_type(4))) float;

typedef __attribute__((address_space(1))) const void as1_void;
typedef __attribute__((address_space(3))) void       as3_void;

#define NROWS 32768   // B*H*W*D / 256 rows after reshape(-1,256)
#define NDIM  256
#define KCODES 8192
#define ND_TOT 8388608
#define NT 32         // n-tiles (of 128 codes) per block (half the codebook)
#define CBSCALE 8192.0f   // lifts codebook (+-1.2e-4) into e4m3 range; argmax invariant

// ---------------- prep: z -> fp8 (x1), cb -> fp8 (x8192), fused ----------------
__global__ __launch_bounds__(256) void prep_fp8_kernel(const float* __restrict__ z,
                                                       const float* __restrict__ cb,
                                                       u32* __restrict__ zb8,
                                                       u32* __restrict__ cbb8) {
    int gid = blockIdx.x * 256 + threadIdx.x;
    const float* src; char* dst; float sc; int base;
    if (gid < ND_TOT / 16) { src = z;  dst = (char*)zb8;  sc = 1.0f;    base = gid * 16; }
    else { src = cb; dst = (char*)cbb8; sc = CBSCALE; base = (gid - ND_TOT / 16) * 16; }
    uint4 o;
    #pragma unroll
    for (int q = 0; q < 4; q++) {
        float4 v = *(const float4*)(src + base + q * 4);
        int r = __builtin_amdgcn_cvt_pk_fp8_f32(v.x * sc, v.y * sc, 0, false);
        r     = __builtin_amdgcn_cvt_pk_fp8_f32(v.z * sc, v.w * sc, r, true);
        ((u32*)&o)[q] = (u32)r;
    }
    *(uint4*)(dst + base) = o;   // fp8: byte index == element index
}

// ---------------- fused GEMM + argmax, MX-fp8 K=128 ----------------
// Block = 128 m-rows x half codebook. A (64 rows x 256 K fp8/wave = 64 VGPRs)
// in regs. B streams through 4 x 16KB ring (chunk = 128 codes x 128 K fp8),
// staged two intervals ahead; raw s_barrier + s_waitcnt vmcnt(4) keeps the
// next chunk's DMA in flight across the barrier (R5 structure, verified).
// MFMA = mfma_scale_f32_16x16x128_f8f6f4, scales fixed at 1.0 (E8M0=127);
// operand layout = K-contiguous 32B/lane (k = quad*32+[0..32)), the layout
// m148's HW-verified ladder port uses. 16 MFMA + 8 ds_read_b128 per chunk.
// LDS unit swizzle u ^= (row&7): same 8-lane/4-bank density that measured
// 0 conflicts in R1-R5. Packed-key argmax: bias 2048 (scores 2048+-303 > 0,
// float order == int order), col in low 13 mantissa bits.
__global__ __launch_bounds__(256, 2) void vq_scores_kernel(const u32* __restrict__ zb8,
                                                           const u32* __restrict__ cbb8,
                                                           u32* __restrict__ slots) {
    __shared__ __align__(16) char Bs[4][16384];      // 4 x 16 KB ring

    int bid  = blockIdx.x;
    int half = bid & 1;
    int m0   = (bid >> 1) * 128;
    int nbase = half * (KCODES / 2);
    int tid  = threadIdx.x;
    int lane = tid & 63;
    int w    = tid >> 6;         // 2x2 wave grid
    int wm = w >> 1, wn = w & 1;
    int l15 = lane & 15, quad = lane >> 4;

    // ---- one-time A prologue: wave's 64 rows x 256 K fp8 -> 64 VGPRs ----
    i32x8 A8[2][4];              // [kstep(128-wide)][mfrag(16 rows)]
    {
        const char* zb = (const char*)zb8 + (size_t)(m0 + wm * 64) * NDIM;
        #pragma unroll
        for (int ks = 0; ks < 2; ks++)
            #pragma unroll
            for (int i = 0; i < 4; i++) {
                const char* p = zb + (size_t)(i * 16 + l15) * NDIM + ks * 128 + quad * 32;
                union { int4 q[2]; i32x8 v; } u;
                u.q[0] = *(const int4*)p;
                u.q[1] = *(const int4*)(p + 16);
                A8[ks][i] = u.v;
            }
    }

    // stage chunk cw (tile cw>>1, K-half cw&1): 4 global_load_lds per lane,
    // 16B-unit swizzle u^=(row&7), dest = wave-uniform base + lane*16
    auto stage = [&](int cw) {
        const char* src = (const char*)cbb8
                        + (size_t)(nbase + (cw >> 1) * 128) * NDIM + (cw & 1) * 128;
        #pragma unroll
        for (int s2 = 0; s2 < 4; s2++) {
            int p  = s2 * 256 + w * 64 + lane;        // 16B unit id in chunk
            int rb = p >> 3;                          // B row (code)
            int uu = (p & 7) ^ (rb & 7);              // swizzled unit
            const char* g = src + (size_t)rb * NDIM + uu * 16;
            int ldsoff = (cw & 3) * 16384 + p * 16;
            __builtin_amdgcn_global_load_lds((as1_void*)g,
                (as3_void*)(&Bs[0][0] + ldsoff), 16, 0, 0);
        }
    };

    f32x4 acc[4][4];
    float mkey[16];
    #pragma unroll
    for (int s = 0; s < 16; s++) mkey[s] = 0.f;

    stage(0);
    stage(1);

    #pragma unroll 1
    for (int t = 0; t < NT; t++) {
        // acc init = +2048 bias => scores positive => float order == int order
        #pragma unroll
        for (int i = 0; i < 4; i++)
            #pragma unroll
            for (int j = 0; j < 4; j++)
                acc[i][j] = (f32x4){2048.f, 2048.f, 2048.f, 2048.f};

        #pragma unroll
        for (int ks = 0; ks < 2; ks++) {     // two 128-K chunks of this tile
            int ci = t * 2 + ks;
            stage((ci + 2) & 63);            // wrap: dummy restage of a dead buf
            // retire all but newest 4 DMAs (chunk ci resident), raw barrier:
            // chunk ci+2 stays in flight across it. No vmcnt(0) drain.
            __asm__ volatile("s_waitcnt vmcnt(4)\n\ts_barrier" ::: "memory");

            i32x8 bg[4];
            #pragma unroll
            for (int j = 0; j < 4; j++) {
                int rb = wn * 64 + j * 16 + l15;
                const char* bp = &Bs[0][0] + (ci & 3) * 16384 + rb * 128;
                union { int4 q[2]; i32x8 v; } u;
                u.q[0] = *(const int4*)(bp + ((((quad * 2)     ^ (rb & 7))) << 4));
                u.q[1] = *(const int4*)(bp + ((((quad * 2 + 1) ^ (rb & 7))) << 4));
                bg[j] = u.v;
            }
            #pragma unroll
            for (int i = 0; i < 4; i++)
                #pragma unroll
                for (int j = 0; j < 4; j++)
                    acc[i][j] = __builtin_amdgcn_mfma_scale_f32_16x16x128_f8f6f4(
                                    A8[ks][i], bg[j], acc[i][j],
                                    0, 0,                       // cbsz/blgp: fp8 e4m3
                                    0, 0x7F7F7F7F,              // scale A = 1.0
                                    0, 0x7F7F7F7F);             // scale B = 1.0
        }

        // packed-key argmax update: 2 VALU per element (v_and_or_b32 + v_max_f32)
        int cb0 = nbase + t * 128 + wn * 64 + l15;
        #pragma unroll
        for (int i = 0; i < 4; i++)
            #pragma unroll
            for (int r = 0; r < 4; r++) {
                int s = i * 4 + r;
                #pragma unroll
                for (int j = 0; j < 4; j++) {
                    u32 p = (__float_as_uint(acc[i][j][r]) & 0xFFFFE000u) | (u32)(cb0 + j * 16);
                    mkey[s] = fmaxf(mkey[s], __uint_as_float(p));
                }
            }
    }

    // one-time reduction across the 16 col-lanes; plain u32 store per row
    #pragma unroll
    for (int s = 0; s < 16; s++) {
        float v = mkey[s];
        #pragma unroll
        for (int sh = 1; sh < 16; sh <<= 1)
            v = fmaxf(v, __shfl_xor(v, sh, 64));
        if (l15 == s) {   // one writer per 16-lane group (4 quads -> 4 rows)
            int i = s >> 2, r = s & 3;
            int row = m0 + wm * 64 + i * 16 + quad * 4 + r;
            slots[(size_t)(half * 2 + wn) * NROWS + row] = __float_as_uint(v);
        }
    }
}

// ---------------- gather + straight-through + loss partials ----------------
__global__ __launch_bounds__(256) void gather_loss_kernel(const float* __restrict__ z,
                                                          const float* __restrict__ cb,
                                                          const u32* __restrict__ slots,
                                                          float* __restrict__ out,
                                                          float* __restrict__ part) {
    __shared__ u32 lidx[16];
    __shared__ float partial[4];
    int tid = threadIdx.x;
    int n0 = blockIdx.x * 16;                 // 16 rows per block
    if (tid < 16) {
        int row = n0 + tid;
        u32 k0 = slots[row];
        u32 k1 = slots[(size_t)NROWS + row];
        u32 k2 = slots[(size_t)2 * NROWS + row];
        u32 k3 = slots[(size_t)3 * NROWS + row];
        u32 a = k0 > k1 ? k0 : k1;
        u32 b = k2 > k3 ? k2 : k3;
        lidx[tid] = (a > b ? a : b) & 0x1FFFu;   // low 13 bits = argmax col
    }
    __syncthreads();
    int lane = tid & 63;
    int w = tid >> 6;
    int d = lane * 4;
    float s = 0.f;
    #pragma unroll
    for (int g = 0; g < 4; g++) {
        int rl = g * 4 + w;
        size_t zoff = (size_t)(n0 + rl) * NDIM + d;
        u32 idx = lidx[rl];
        float4 zv = *(const float4*)(z + zoff);
        float4 qv = *(const float4*)(cb + (size_t)idx * NDIM + d);
        float4 o;
        o.x = zv.x + (qv.x - zv.x);           // straight-through, matches ref fp ops
        o.y = zv.y + (qv.y - zv.y);
        o.z = zv.z + (qv.z - zv.z);
        o.w = zv.w + (qv.w - zv.w);
        *(float4*)(out + zoff) = o;
        float dx = zv.x - qv.x, dy = zv.y - qv.y, dz = zv.z - qv.z, dw = zv.w - qv.w;
        s += dx*dx + dy*dy + dz*dz + dw*dw;
    }
    #pragma unroll
    for (int off = 32; off > 0; off >>= 1) s += __shfl_down(s, off, 64);
    if (lane == 0) partial[w] = s;
    __syncthreads();
    if (tid == 0)
        part[blockIdx.x] = (partial[0] + partial[1]) + (partial[2] + partial[3]);
}

// ---------------- final loss reduction (2048 partials) ----------------
__global__ __launch_bounds__(256) void loss_reduce_kernel(const float* __restrict__ part,
                                                          float* __restrict__ loss) {
    __shared__ float ps[4];
    int tid = threadIdx.x;
    float s = 0.f;
    #pragma unroll
    for (int k = 0; k < 8; k++) s += part[tid + k * 256];
    #pragma unroll
    for (int off = 32; off > 0; off >>= 1) s += __shfl_down(s, off, 64);
    int lane = tid & 63, w = tid >> 6;
    if (lane == 0) ps[w] = s;
    __syncthreads();
    if (tid == 0)
        loss[0] = ((ps[0] + ps[1]) + (ps[2] + ps[3])) * (1.25f / 8388608.f);
}

extern "C" void kernel_launch(void* const* d_in, const int* in_sizes, int n_in,
                              void* d_out, int out_size, void* d_ws, size_t ws_size,
                              hipStream_t stream) {
    const float* z  = (const float*)d_in[0];   // 8*256*64*64 fp32
    const float* cb = (const float*)d_in[1];   // 8192*256 fp32
    float* out = (float*)d_out;                // 8388608 quantized_st + 1 loss

    char* ws = (char*)d_ws;
    u32* zb8    = (u32*)ws;                                 // 8 MB  (z fp8)
    u32* cbb8   = (u32*)(ws + 8388608);                     // 2 MB  (cb fp8 * 8192)
    u32* slots  = (u32*)(ws + 8388608 + 2097152);           // 512 KB (4 slots/row)
    float* part = (float*)(ws + 8388608 + 2097152 + 524288);// 8 KB
    float* loss = out + ND_TOT;

    prep_fp8_kernel<<<(ND_TOT / 16 + KCODES * NDIM / 16) / 256, 256, 0, stream>>>(z, cb, zb8, cbb8);
    vq_scores_kernel<<<(NROWS / 128) * 2, 256, 0, stream>>>(zb8, cbb8, slots);
    gather_loss_kernel<<<NROWS / 16, 256, 0, stream>>>(z, cb, slots, out, part);
    loss_reduce_kernel<<<1, 256, 0, stream>>>(part, loss);
}